// Round 5
// baseline (82.311 us; speedup 1.0000x reference)
//
#include <hip/hip_runtime.h>

// Simple_TensorProduct (e3nn uvw TP, MUL=256, l<=1, v=1) as two fused bf16 GEMMs.
//   out0[z,w]      = sum_k T0[z,k]    * B0[k,w]   (K=512)
//   out1[(z,c),w]  = sum_k T1[(z,c),k]* B1[k,w]   (K=768, M=3N)
// T = x1 with x2 folded in (built per z-tile, bf16, LDS, A-fragment order).
// B = weights, prescaled by path alphas, bf16, B-fragment order in d_ws.
//
// R5: 512-thread blocks (8 waves), z=16, u=128 (2 chunks, fewest serial
// steps), ct=2 per wave -> acc = 8 f32x4 = 32 AGPR/wave. This fits a
// 128-reg/4-waves-per-SIMD budget WITH an explicit 2-deep B prefetch
// (ILP) — R2-R4 showed TLP and ILP individually saturate; this buys both.
// LDS 45 KB; grid 1250.

typedef short bf16x8 __attribute__((ext_vector_type(8)));
typedef float f32x4 __attribute__((ext_vector_type(4)));

static __device__ __forceinline__ unsigned short f2bf(float f) {
  unsigned int u = __builtin_bit_cast(unsigned int, f);
  u += 0x7FFFu + ((u >> 16) & 1u);   // RNE
  return (unsigned short)(u >> 16);
}

static __device__ __forceinline__ bf16x8 asbf(int4 v) {
  return __builtin_bit_cast(bf16x8, v);
}

// ---------------------------------------------------------------------------
// Weight prep (u-chunk = 128, c in {0,1}; same layout as the passing R2):
// B1 region: fid = ((c*12+kt)*16+ct)*64+lane   (24576 frags, 393216 B)
// B0 region: fid = 24576 + ((c*8+kt)*16+ct)*64+lane (16384 frags, 262144 B)
// elem e: kc = kt*32+(lane>>4)*8+e, w = ct*16+(lane&15), u = c*128+(kc&127)
// ---------------------------------------------------------------------------
__global__ __launch_bounds__(256) void prep_weights(
    const float* __restrict__ wgt, unsigned short* __restrict__ Bw)
{
  int fid = blockIdx.x * 256 + threadIdx.x;
  union { unsigned short h[8]; int4 v; } pk;
  if (fid < 24576) {
    // B1: seg0->W2*(A1/sqrt3), seg1->W3*(A1/sqrt3), seg2->W5*(A1/sqrt6)
    int lane = fid & 63;
    int ct = (fid >> 6) & 15;
    int q = fid >> 10;            // 0..23
    int kt = q % 12, c = q / 12;
    int w = ct * 16 + (lane & 15);
    int kh = (lane >> 4) * 8;
#pragma unroll
    for (int e = 0; e < 8; ++e) {
      int kc = kt * 32 + kh + e;       // 0..383
      int seg = kc >> 7;
      int u = c * 128 + (kc & 127);
      float s  = (seg == 2) ? 0.025515518153991442f : 0.03608439182435161f;
      int off  = (seg == 0) ? 65536 : (seg == 1 ? 131072 : 262144);
      pk.h[e] = f2bf(wgt[off + u * 256 + w] * s);
    }
    ((int4*)Bw)[fid] = pk.v;
  } else if (fid < 40960) {
    // B0: seg0->W1*A0, seg1->W4*(A0/sqrt3)
    int f2 = fid - 24576;
    int lane = f2 & 63;
    int ct = (f2 >> 6) & 15;
    int q = f2 >> 10;             // 0..15
    int kt = q & 7, c = q >> 3;
    int w = ct * 16 + (lane & 15);
    int kh = (lane >> 4) * 8;
#pragma unroll
    for (int e = 0; e < 8; ++e) {
      int kc = kt * 32 + kh + e;       // 0..255
      int seg = kc >> 7;
      int u = c * 128 + (kc & 127);
      float s  = (seg == 0) ? 0.04419417382415922f : 0.025515518153991442f;
      int off  = (seg == 0) ? 0 : 196608;
      pk.h[e] = f2bf(wgt[off + u * 256 + w] * s);
    }
    ((int4*)Bw)[fid] = pk.v;
  }
}

// LDS map (int4 slots): T1 rt*768 + kt*64 + perm  (rt 0..2, kt 0..11)
//                       T0 2304 + kt*64 + perm    (kt 0..7)
#define T0BASE 2304

struct X1Regs {
  float4 s;      // s1[u .. u+4)
  float4 v[3];   // v1[(u..u+4), 0..3) interleaved: f[3e+k]
};

static __device__ __forceinline__ void load_x1(
    X1Regs& r, const float* __restrict__ x1, int zrow, int ub, int rr)
{
  const float* base = x1 + (size_t)zrow * 1024;
  r.s = *(const float4*)(base + ub + rr * 4);
  const float4* pv = (const float4*)(base + 256 + 3 * ub + rr * 12);
#pragma unroll
  for (int i = 0; i < 3; ++i) r.v[i] = pv[i];
}

// thread (zl 0..15, rr 0..31) owns u-run [rr*4, rr*4+4) of the 128-u chunk.
// kc = sg*128 + rr*4 + e -> kt = sg*4 + (rr>>3); lh = (rr>>1)&3; half = rr&1.
static __device__ __forceinline__ void build_frags(
    const X1Regs& r, int zl, int rr, float s2, const float* v2, int4* ldsT)
{
  union { float4 q; float f[4]; } s1u;
  s1u.q = r.s;
  union { float4 q[3]; float f[12]; } v1u;
#pragma unroll
  for (int i = 0; i < 3; ++i) v1u.q[i] = r.v[i];
  const int lh   = (rr >> 1) & 3;
  const int kq   = rr >> 3;
  const int half = rr & 1;
  int2* lds2 = (int2*)ldsT;

  // ---- T1: seg 0..2 x comp k 0..2 ; row = 3*zl + k (0..47)
#pragma unroll
  for (int sg = 0; sg < 3; ++sg) {
#pragma unroll
    for (int k = 0; k < 3; ++k) {
      int row = 3 * zl + k;
      int kt  = sg * 4 + kq;
      int fl  = (((lh << 4) | (row & 15)) ^ (kt & 7)) ^ lh;
      int slot = (row >> 4) * 768 + kt * 64 + fl;
      float t[4];
      if (sg == 0) {                     // s1 * v2[k]      (-> W2)
#pragma unroll
        for (int e = 0; e < 4; ++e) t[e] = s1u.f[e] * v2[k];
      } else if (sg == 1) {              // v1[.,k] * s2    (-> W3)
#pragma unroll
        for (int e = 0; e < 4; ++e) t[e] = v1u.f[3 * e + k] * s2;
      } else {                           // (v1 x v2)[k]    (-> W5)
        int k1 = k + 1; if (k1 > 2) k1 -= 3;
        int k2 = k + 2; if (k2 > 2) k2 -= 3;
#pragma unroll
        for (int e = 0; e < 4; ++e)
          t[e] = v1u.f[3 * e + k1] * v2[k2] - v1u.f[3 * e + k2] * v2[k1];
      }
      union { unsigned short h[4]; int2 v; } pk;
#pragma unroll
      for (int e = 0; e < 4; ++e) pk.h[e] = f2bf(t[e]);
      lds2[slot * 2 + half] = pk.v;
    }
  }
  // ---- T0: seg 0..1 ; row = zl (0..15)
#pragma unroll
  for (int sg = 0; sg < 2; ++sg) {
    int kt = sg * 4 + kq;
    int fl = (((lh << 4) | zl) ^ (kt & 7)) ^ lh;
    int slot = T0BASE + kt * 64 + fl;
    float t[4];
    if (sg == 0) {                       // s1 * s2         (-> W1)
#pragma unroll
      for (int e = 0; e < 4; ++e) t[e] = s1u.f[e] * s2;
    } else {                             // v1 . v2         (-> W4)
#pragma unroll
      for (int e = 0; e < 4; ++e)
        t[e] = v1u.f[3 * e] * v2[0] + v1u.f[3 * e + 1] * v2[1]
             + v1u.f[3 * e + 2] * v2[2];
    }
    union { unsigned short h[4]; int2 v; } pk;
#pragma unroll
    for (int e = 0; e < 4; ++e) pk.h[e] = f2bf(t[e]);
    lds2[slot * 2 + half] = pk.v;
  }
}

// Per-wave GEMM over one u-chunk, ct pair {ct0, ct0+1}. 2-deep B prefetch:
// B for step s+2 issued while MFMA-ing step s (compiler emits counted vmcnt).
static __device__ __forceinline__ void gemm_chunk(
    int c, int lane, int ct0, const int4* ldsT,
    const int4* __restrict__ B1v, const int4* __restrict__ B0v,
    f32x4 acc1[3][2], f32x4 acc0[2])
{
  // ---- out1: 12 kt steps, 6 MFMA each
  {
    const int4* base = B1v + ((size_t)(c * 12) * 16 + ct0) * 64 + lane;
    int4 b0[2], b1[2];
    b0[0] = base[0];    b0[1] = base[64];
    b1[0] = base[1024]; b1[1] = base[1024 + 64];
#pragma unroll 1
    for (int kt = 0; kt < 12; ++kt) {
      int4 bf[2];
      if (kt < 10) {
        bf[0] = base[(kt + 2) * 1024];
        bf[1] = base[(kt + 2) * 1024 + 64];
      } else {
        bf[0] = b0[0]; bf[1] = b0[1];
      }
      int fl = (lane ^ (kt & 7)) ^ (lane >> 4);
      int4 a0 = ldsT[kt * 64 + fl];
      int4 a1 = ldsT[768 + kt * 64 + fl];
      int4 a2 = ldsT[1536 + kt * 64 + fl];
      int4 a[3] = {a0, a1, a2};
#pragma unroll
      for (int rt = 0; rt < 3; ++rt) {
        bf16x8 av = asbf(a[rt]);
#pragma unroll
        for (int j = 0; j < 2; ++j)
          acc1[rt][j] = __builtin_amdgcn_mfma_f32_16x16x32_bf16(
              av, asbf(b0[j]), acc1[rt][j], 0, 0, 0);
      }
      b0[0] = b1[0]; b0[1] = b1[1];
      b1[0] = bf[0]; b1[1] = bf[1];
    }
  }
  // ---- out0: 8 kt steps, 2 MFMA each
  {
    const int4* base = B0v + ((size_t)(c * 8) * 16 + ct0) * 64 + lane;
    int4 b0[2], b1[2];
    b0[0] = base[0];    b0[1] = base[64];
    b1[0] = base[1024]; b1[1] = base[1024 + 64];
#pragma unroll 1
    for (int kt = 0; kt < 8; ++kt) {
      int4 bf[2];
      if (kt < 6) {
        bf[0] = base[(kt + 2) * 1024];
        bf[1] = base[(kt + 2) * 1024 + 64];
      } else {
        bf[0] = b0[0]; bf[1] = b0[1];
      }
      int fl = (lane ^ (kt & 7)) ^ (lane >> 4);
      int4 a0 = ldsT[T0BASE + kt * 64 + fl];
      bf16x8 av = asbf(a0);
#pragma unroll
      for (int j = 0; j < 2; ++j)
        acc0[j] = __builtin_amdgcn_mfma_f32_16x16x32_bf16(
            av, asbf(b0[j]), acc0[j], 0, 0, 0);
      b0[0] = b1[0]; b0[1] = b1[1];
      b1[0] = bf[0]; b1[1] = bf[1];
    }
  }
}

// ---------------------------------------------------------------------------
// Main kernel: 16 z-rows per block, 512 threads (8 waves, ct=2 each),
// full 256 out-cols. LDS = 2816 int4 = 45 KB. 2 u-chunks of 128; chunk-1
// x1 loads issued before gemm(0).
// ---------------------------------------------------------------------------
__global__ __launch_bounds__(512, 4) void tp_main(
    const float* __restrict__ x1, const float* __restrict__ x2,
    const int4* __restrict__ B1v, const int4* __restrict__ B0v,
    float* __restrict__ out)
{
  __shared__ int4 ldsT[2816];           // 45056 bytes
  const int tid  = threadIdx.x;
  const int lane = tid & 63;
  const int wid  = tid >> 6;            // wave 0..7
  const int ct0  = wid * 2;             // this wave's two 16-col tiles
  const int z0   = blockIdx.x * 16;
  const int zl   = tid >> 5;            // T-build row ownership (0..15)
  const int rr   = tid & 31;            // T-build u-run ownership (0..31)

  f32x4 acc1[3][2];
  f32x4 acc0[2];
#pragma unroll
  for (int i = 0; i < 3; ++i)
#pragma unroll
    for (int j = 0; j < 2; ++j) acc1[i][j] = (f32x4){0.f, 0.f, 0.f, 0.f};
#pragma unroll
  for (int j = 0; j < 2; ++j) acc0[j] = (f32x4){0.f, 0.f, 0.f, 0.f};

  // x2 row values (broadcast per 32 threads)
  float4 x2v = ((const float4*)x2)[z0 + zl];
  const float s2 = x2v.x;
  float v2[3] = {x2v.y, x2v.z, x2v.w};

  X1Regs r;
  load_x1(r, x1, z0 + zl, 0, rr);
  build_frags(r, zl, rr, s2, v2, ldsT);
  __syncthreads();

  load_x1(r, x1, z0 + zl, 128, rr);     // chunk 1 in flight under gemm(0)
  gemm_chunk(0, lane, ct0, ldsT, B1v, B0v, acc1, acc0);
  __syncthreads();
  build_frags(r, zl, rr, s2, v2, ldsT);
  __syncthreads();

  gemm_chunk(1, lane, ct0, ldsT, B1v, B0v, acc1, acc0);

  // ---- epilogue: accumulators are the final outputs
  const int col = lane & 15;
  const int rb  = (lane >> 4) * 4;       // C/D: col=lane&15, row=(lane>>4)*4+reg
#pragma unroll
  for (int j = 0; j < 2; ++j) {
    int w = (ct0 + j) * 16 + col;
#pragma unroll
    for (int rg = 0; rg < 4; ++rg) {
      int row = rb + rg;                 // zl 0..15
      out[(size_t)(z0 + row) * 1024 + w] = acc0[j][rg];
    }
  }
#pragma unroll
  for (int rt = 0; rt < 3; ++rt) {
#pragma unroll
    for (int j = 0; j < 2; ++j) {
      int w = (ct0 + j) * 16 + col;
#pragma unroll
      for (int rg = 0; rg < 4; ++rg) {
        int row = rt * 16 + rb + rg;     // 0..47 ; row = 3*zl + k
        int zz = row / 3;
        int k  = row - zz * 3;
        out[(size_t)(z0 + zz) * 1024 + 256 + w * 3 + k] = acc1[rt][j][rg];
      }
    }
  }
}

// ---------------------------------------------------------------------------
extern "C" void kernel_launch(void* const* d_in, const int* in_sizes, int n_in,
                              void* d_out, int out_size, void* d_ws, size_t ws_size,
                              hipStream_t stream) {
  const float* x1  = (const float*)d_in[0];   // (n, 1024) f32
  const float* x2  = (const float*)d_in[1];   // (n, 4)    f32
  const float* wgt = (const float*)d_in[2];   // (327680,) f32
  float* out = (float*)d_out;                 // (n, 1024) f32

  // ws: B1 fragments [0, 393216) + B0 fragments [393216, 655360)  (bf16)
  unsigned short* Bw = (unsigned short*)d_ws;
  const int4* B1v = (const int4*)Bw;
  const int4* B0v = B1v + 24576;

  int n = in_sizes[0] / 1024;                 // 20000 (divisible by 16)

  prep_weights<<<160, 256, 0, stream>>>(wgt, Bw);
  tp_main<<<n / 16, 512, 0, stream>>>(x1, x2, B1v, B0v, out);
}

// Round 6
// 80.839 us; speedup vs baseline: 1.0182x; 1.0182x over previous
//
#include <hip/hip_runtime.h>

// Simple_TensorProduct (e3nn uvw TP, MUL=256, l<=1, v=1) as two fused bf16 GEMMs.
//   out0[z,w]      = sum_k T0[z,k]    * B0[k,w]   (K=512)
//   out1[(z,c),w]  = sum_k T1[(z,c),k]* B1[k,w]   (K=768, M=3N)
// T = x1 with x2 folded in (built per z-tile, bf16, LDS, A-fragment order).
// B = weights, prescaled by path alphas, bf16, B-fragment order in d_ws.
//
// R6: break the compiler's serialization. (1) gemm fully unrolled (10 static
// steps per u-chunk) with static-indexed 2-deep B prefetch rotation.
// (2) double-buffered LDS (2 x 22.5 KB): build(c+1) overlaps gemm(c) in the
// same barrier-free region -> build VALU + x1 loads fill gemm load shadows.
// 512 thr, z=16, u=64 x 4 chunks, ct=2/wave (acc 32 AGPR), 5 barriers total.

typedef short bf16x8 __attribute__((ext_vector_type(8)));
typedef float f32x4 __attribute__((ext_vector_type(4)));

static __device__ __forceinline__ unsigned short f2bf(float f) {
  unsigned int u = __builtin_bit_cast(unsigned int, f);
  u += 0x7FFFu + ((u >> 16) & 1u);   // RNE
  return (unsigned short)(u >> 16);
}

static __device__ __forceinline__ bf16x8 asbf(int4 v) {
  return __builtin_bit_cast(bf16x8, v);
}

// ---------------------------------------------------------------------------
// Weight prep (u-chunk = 64, c in 0..3; layout as passing R3/R4):
// B1: fid = ((c*6+kt)*16+ct)*64+lane; elem e: kc=kt*32+(lane>>4)*8+e (0..191),
//     seg=kc>>6, u=c*64+(kc&63), w=ct*16+(lane&15)
// B0: fid = 24576 + ((c*4+kt)*16+ct)*64+lane; kc 0..127, seg=kc>>6
// ---------------------------------------------------------------------------
__global__ __launch_bounds__(256) void prep_weights(
    const float* __restrict__ wgt, unsigned short* __restrict__ Bw)
{
  int fid = blockIdx.x * 256 + threadIdx.x;
  union { unsigned short h[8]; int4 v; } pk;
  if (fid < 24576) {
    int lane = fid & 63;
    int ct = (fid >> 6) & 15;
    int q = fid >> 10;            // 0..23 = c*6 + kt
    int kt = q % 6, c = q / 6;
    int w = ct * 16 + (lane & 15);
    int kh = (lane >> 4) * 8;
#pragma unroll
    for (int e = 0; e < 8; ++e) {
      int kc = kt * 32 + kh + e;       // 0..191
      int seg = kc >> 6;
      int u = c * 64 + (kc & 63);
      float s  = (seg == 2) ? 0.025515518153991442f : 0.03608439182435161f;
      int off  = (seg == 0) ? 65536 : (seg == 1 ? 131072 : 262144);
      pk.h[e] = f2bf(wgt[off + u * 256 + w] * s);
    }
    ((int4*)Bw)[fid] = pk.v;
  } else if (fid < 40960) {
    int f2 = fid - 24576;
    int lane = f2 & 63;
    int ct = (f2 >> 6) & 15;
    int q = f2 >> 10;             // 0..15 = c*4 + kt
    int kt = q & 3, c = q >> 2;
    int w = ct * 16 + (lane & 15);
    int kh = (lane >> 4) * 8;
#pragma unroll
    for (int e = 0; e < 8; ++e) {
      int kc = kt * 32 + kh + e;       // 0..127
      int seg = kc >> 6;
      int u = c * 64 + (kc & 63);
      float s  = (seg == 0) ? 0.04419417382415922f : 0.025515518153991442f;
      int off  = (seg == 0) ? 0 : 196608;
      pk.h[e] = f2bf(wgt[off + u * 256 + w] * s);
    }
    ((int4*)Bw)[fid] = pk.v;
  }
}

// Per-buffer LDS map (int4 slots): T1 rt*384 + kt*64 + perm (rt 0..2, kt 0..5)
//                                  T0 1152 + kt*64 + perm   (kt 0..3)
// Buffer b at slot offset b*1408. Total 2816 int4 = 45056 B.
#define BUFSLOTS 1408
#define T0BASE 1152

struct X1R {
  float2 s;      // s1[u, u+1]
  float2 v[3];   // v1[(u,u+1), 0..3): f[3e+k] = v[(3e+k)>>1] .x/.y
};

static __device__ __forceinline__ void load_x1(
    X1R& r, const float* __restrict__ x1, int zrow, int ub, int rr)
{
  const float* base = x1 + (size_t)zrow * 1024;
  r.s = *(const float2*)(base + ub + rr * 2);
  const float2* pv = (const float2*)(base + 256 + 3 * ub + rr * 6);
  r.v[0] = pv[0]; r.v[1] = pv[1]; r.v[2] = pv[2];
}

// thread (zl 0..15, rr 0..31) owns u-pair [rr*2, rr*2+2) of the 64-u chunk.
// kc = sg*64 + rr*2 -> kt = sg*2 + (rr>>4); lh = (rr>>2)&3; dword q = rr&3.
static __device__ __forceinline__ void build_frags(
    const X1R& r, int zl, int rr, float s2, const float* v2,
    unsigned int* __restrict__ lds32)
{
  float s1f[2] = {r.s.x, r.s.y};
  float v1f[6] = {r.v[0].x, r.v[0].y, r.v[1].x, r.v[1].y, r.v[2].x, r.v[2].y};
  const int lh = (rr >> 2) & 3;
  const int kq = rr >> 4;
  const int q  = rr & 3;

  // ---- T1: seg 0..2 x comp k 0..2 ; row = 3*zl + k (0..47)
#pragma unroll
  for (int sg = 0; sg < 3; ++sg) {
#pragma unroll
    for (int k = 0; k < 3; ++k) {
      int row = 3 * zl + k;
      int kt  = sg * 2 + kq;
      int fl  = (((lh << 4) | (row & 15)) ^ (kt & 7)) ^ lh;
      int slot = (row >> 4) * 384 + kt * 64 + fl;
      float t0, t1;
      if (sg == 0) {                     // s1 * v2[k]      (-> W2)
        t0 = s1f[0] * v2[k]; t1 = s1f[1] * v2[k];
      } else if (sg == 1) {              // v1[.,k] * s2    (-> W3)
        t0 = v1f[k] * s2; t1 = v1f[3 + k] * s2;
      } else {                           // (v1 x v2)[k]    (-> W5)
        int k1 = k + 1; if (k1 > 2) k1 -= 3;
        int k2 = k + 2; if (k2 > 2) k2 -= 3;
        t0 = v1f[k1] * v2[k2] - v1f[k2] * v2[k1];
        t1 = v1f[3 + k1] * v2[k2] - v1f[3 + k2] * v2[k1];
      }
      unsigned int pk = (unsigned int)f2bf(t0) | ((unsigned int)f2bf(t1) << 16);
      lds32[slot * 4 + q] = pk;
    }
  }
  // ---- T0: seg 0..1 ; row = zl (0..15)
#pragma unroll
  for (int sg = 0; sg < 2; ++sg) {
    int kt = sg * 2 + kq;
    int fl = (((lh << 4) | zl) ^ (kt & 7)) ^ lh;
    int slot = T0BASE + kt * 64 + fl;
    float t0, t1;
    if (sg == 0) {                       // s1 * s2         (-> W1)
      t0 = s1f[0] * s2; t1 = s1f[1] * s2;
    } else {                             // v1 . v2         (-> W4)
      t0 = v1f[0] * v2[0] + v1f[1] * v2[1] + v1f[2] * v2[2];
      t1 = v1f[3] * v2[0] + v1f[4] * v2[1] + v1f[5] * v2[2];
    }
    unsigned int pk = (unsigned int)f2bf(t0) | ((unsigned int)f2bf(t1) << 16);
    lds32[slot * 4 + q] = pk;
  }
}

// B fragment pair for step s (s<6: out1 kt=s; s>=6: out0 kt=s-6)
static __device__ __forceinline__ void load_B(
    int4 (&b)[2], const int4* __restrict__ B1v, const int4* __restrict__ B0v,
    int c, int s, int ct0, int lane)
{
  const int4* p = (s < 6)
      ? B1v + ((size_t)((c * 6 + s) * 16 + ct0)) * 64 + lane
      : B0v + ((size_t)((c * 4 + (s - 6)) * 16 + ct0)) * 64 + lane;
  b[0] = p[0]; b[1] = p[64];
}

// Fully-unrolled 10-step GEMM for one u-chunk. bb holds steps {0,1} on entry.
static __device__ __forceinline__ void gemm_steps(
    int c, const int4* __restrict__ buf, int4 (&bb)[3][2],
    const int4* __restrict__ B1v, const int4* __restrict__ B0v,
    int ct0, int lane, f32x4 acc1[3][2], f32x4 acc0[2])
{
#pragma unroll
  for (int s = 0; s < 10; ++s) {
    if (s + 2 < 10)
      load_B(bb[(s + 2) % 3], B1v, B0v, c, s + 2, ct0, lane);
    int4 (&b)[2] = bb[s % 3];
    if (s < 6) {
      int kt = s;
      int fl = (lane ^ (kt & 7)) ^ (lane >> 4);
      int4 a0 = buf[kt * 64 + fl];
      int4 a1 = buf[384 + kt * 64 + fl];
      int4 a2 = buf[768 + kt * 64 + fl];
      int4 a[3] = {a0, a1, a2};
#pragma unroll
      for (int rt = 0; rt < 3; ++rt) {
        bf16x8 av = asbf(a[rt]);
#pragma unroll
        for (int j = 0; j < 2; ++j)
          acc1[rt][j] = __builtin_amdgcn_mfma_f32_16x16x32_bf16(
              av, asbf(b[j]), acc1[rt][j], 0, 0, 0);
      }
    } else {
      int kt = s - 6;
      int fl = (lane ^ (kt & 7)) ^ (lane >> 4);
      int4 a0 = buf[T0BASE + kt * 64 + fl];
      bf16x8 av = asbf(a0);
#pragma unroll
      for (int j = 0; j < 2; ++j)
        acc0[j] = __builtin_amdgcn_mfma_f32_16x16x32_bf16(
            av, asbf(b[j]), acc0[j], 0, 0, 0);
    }
  }
}

// ---------------------------------------------------------------------------
// Main: 512 threads (8 waves, ct=2 each), 16 z-rows/block, 4 u-chunks of 64.
// Double-buffered LDS; phase c = { prefetch B(c) | build(c+1) | gemm(c) }.
// ---------------------------------------------------------------------------
__global__ __launch_bounds__(512, 4) void tp_main(
    const float* __restrict__ x1, const float* __restrict__ x2,
    const int4* __restrict__ B1v, const int4* __restrict__ B0v,
    float* __restrict__ out)
{
  __shared__ int4 ldsT[2 * BUFSLOTS];   // 45056 bytes
  const int tid  = threadIdx.x;
  const int lane = tid & 63;
  const int wid  = tid >> 6;            // wave 0..7
  const int ct0  = wid * 2;             // this wave's two 16-col tiles
  const int z0   = blockIdx.x * 16;
  const int zl   = tid >> 5;            // T-build row (0..15)
  const int rr   = tid & 31;            // T-build u-pair (0..31)

  f32x4 acc1[3][2];
  f32x4 acc0[2];
#pragma unroll
  for (int i = 0; i < 3; ++i)
#pragma unroll
    for (int j = 0; j < 2; ++j) acc1[i][j] = (f32x4){0.f, 0.f, 0.f, 0.f};
#pragma unroll
  for (int j = 0; j < 2; ++j) acc0[j] = (f32x4){0.f, 0.f, 0.f, 0.f};

  float4 x2v = ((const float4*)x2)[z0 + zl];
  const float s2 = x2v.x;
  float v2[3] = {x2v.y, x2v.z, x2v.w};

  unsigned int* lds32_0 = (unsigned int*)ldsT;
  unsigned int* lds32_1 = (unsigned int*)(ldsT + BUFSLOTS);

  X1R rA, rB;
  load_x1(rA, x1, z0 + zl, 0, rr);      // chunk 0
  load_x1(rB, x1, z0 + zl, 64, rr);     // chunk 1 (in flight under build 0)
  build_frags(rA, zl, rr, s2, v2, lds32_0);
  __syncthreads();

  int4 bb[3][2];

  // ---- phase 0: gemm(0) from buf0 ; build(1) -> buf1 ; load chunk 2
  load_B(bb[0], B1v, B0v, 0, 0, ct0, lane);
  load_B(bb[1], B1v, B0v, 0, 1, ct0, lane);
  load_x1(rA, x1, z0 + zl, 128, rr);
  build_frags(rB, zl, rr, s2, v2, lds32_1);
  gemm_steps(0, ldsT, bb, B1v, B0v, ct0, lane, acc1, acc0);
  __syncthreads();

  // ---- phase 1: gemm(1) from buf1 ; build(2) -> buf0 ; load chunk 3
  load_B(bb[0], B1v, B0v, 1, 0, ct0, lane);
  load_B(bb[1], B1v, B0v, 1, 1, ct0, lane);
  load_x1(rB, x1, z0 + zl, 192, rr);
  build_frags(rA, zl, rr, s2, v2, lds32_0);
  gemm_steps(1, ldsT + BUFSLOTS, bb, B1v, B0v, ct0, lane, acc1, acc0);
  __syncthreads();

  // ---- phase 2: gemm(2) from buf0 ; build(3) -> buf1
  load_B(bb[0], B1v, B0v, 2, 0, ct0, lane);
  load_B(bb[1], B1v, B0v, 2, 1, ct0, lane);
  build_frags(rB, zl, rr, s2, v2, lds32_1);
  gemm_steps(2, ldsT, bb, B1v, B0v, ct0, lane, acc1, acc0);
  __syncthreads();

  // ---- phase 3: gemm(3) from buf1
  load_B(bb[0], B1v, B0v, 3, 0, ct0, lane);
  load_B(bb[1], B1v, B0v, 3, 1, ct0, lane);
  gemm_steps(3, ldsT + BUFSLOTS, bb, B1v, B0v, ct0, lane, acc1, acc0);

  // ---- epilogue: accumulators are the final outputs
  const int col = lane & 15;
  const int rb  = (lane >> 4) * 4;       // C/D: col=lane&15, row=(lane>>4)*4+reg
#pragma unroll
  for (int j = 0; j < 2; ++j) {
    int w = (ct0 + j) * 16 + col;
#pragma unroll
    for (int rg = 0; rg < 4; ++rg) {
      int row = rb + rg;                 // zl 0..15
      out[(size_t)(z0 + row) * 1024 + w] = acc0[j][rg];
    }
  }
#pragma unroll
  for (int rt = 0; rt < 3; ++rt) {
#pragma unroll
    for (int j = 0; j < 2; ++j) {
      int w = (ct0 + j) * 16 + col;
#pragma unroll
      for (int rg = 0; rg < 4; ++rg) {
        int row = rt * 16 + rb + rg;     // 0..47 ; row = 3*zl + k
        int zz = row / 3;
        int k  = row - zz * 3;
        out[(size_t)(z0 + zz) * 1024 + 256 + w * 3 + k] = acc1[rt][j][rg];
      }
    }
  }
}

// ---------------------------------------------------------------------------
extern "C" void kernel_launch(void* const* d_in, const int* in_sizes, int n_in,
                              void* d_out, int out_size, void* d_ws, size_t ws_size,
                              hipStream_t stream) {
  const float* x1  = (const float*)d_in[0];   // (n, 1024) f32
  const float* x2  = (const float*)d_in[1];   // (n, 4)    f32
  const float* wgt = (const float*)d_in[2];   // (327680,) f32
  float* out = (float*)d_out;                 // (n, 1024) f32

  // ws: B1 fragments [0, 393216) + B0 fragments [393216, 655360)  (bf16)
  unsigned short* Bw = (unsigned short*)d_ws;
  const int4* B1v = (const int4*)Bw;
  const int4* B0v = B1v + 24576;

  int n = in_sizes[0] / 1024;                 // 20000 (divisible by 16)

  prep_weights<<<160, 256, 0, stream>>>(wgt, Bw);
  tp_main<<<n / 16, 512, 0, stream>>>(x1, x2, B1v, B0v, out);
}

// Round 7
// 78.640 us; speedup vs baseline: 1.0467x; 1.0280x over previous
//
#include <hip/hip_runtime.h>

// Simple_TensorProduct (e3nn uvw TP, MUL=256, l<=1, v=1) as two fused bf16 GEMMs.
//   out0[z,w]      = sum_k T0[z,k]    * B0[k,w]   (K=512)
//   out1[(z,c),w]  = sum_k T1[(z,c),k]* B1[k,w]   (K=768, M=3N)
// T = x1 with x2 folded in (built per z-tile, bf16, LDS, A-fragment order).
// B = weights, prescaled by path alphas, bf16, B-fragment order in d_ws.
//
// R7: T14 pattern. Each wave burst-loads its ENTIRE per-chunk B slice
// (20 int4 = 80 VGPR) at phase start, fenced with sched_barrier(0); the
// T-build (VALU) runs as natural latency cover; gemm is pure ds_read+MFMA
// with ZERO global loads. To afford the registers: 256-thr blocks, w-split
// (block covers 128 of 256 cols; grid 2500), launch_bounds(256,3).
// Build/fragment/epilogue math identical to passing R4.

typedef short bf16x8 __attribute__((ext_vector_type(8)));
typedef float f32x4 __attribute__((ext_vector_type(4)));

static __device__ __forceinline__ unsigned short f2bf(float f) {
  unsigned int u = __builtin_bit_cast(unsigned int, f);
  u += 0x7FFFu + ((u >> 16) & 1u);   // RNE
  return (unsigned short)(u >> 16);
}

static __device__ __forceinline__ bf16x8 asbf(int4 v) {
  return __builtin_bit_cast(bf16x8, v);
}

// ---------------------------------------------------------------------------
// Weight prep (u-chunk = 64, c in 0..3; layout as passing R3/R4):
// B1: fid = ((c*6+kt)*16+ct)*64+lane; elem e: kc=kt*32+(lane>>4)*8+e (0..191),
//     seg=kc>>6, u=c*64+(kc&63), w=ct*16+(lane&15)
// B0: fid = 24576 + ((c*4+kt)*16+ct)*64+lane; kc 0..127, seg=kc>>6
// ---------------------------------------------------------------------------
__global__ __launch_bounds__(256) void prep_weights(
    const float* __restrict__ wgt, unsigned short* __restrict__ Bw)
{
  int fid = blockIdx.x * 256 + threadIdx.x;
  union { unsigned short h[8]; int4 v; } pk;
  if (fid < 24576) {
    int lane = fid & 63;
    int ct = (fid >> 6) & 15;
    int q = fid >> 10;            // 0..23 = c*6 + kt
    int kt = q % 6, c = q / 6;
    int w = ct * 16 + (lane & 15);
    int kh = (lane >> 4) * 8;
#pragma unroll
    for (int e = 0; e < 8; ++e) {
      int kc = kt * 32 + kh + e;       // 0..191
      int seg = kc >> 6;
      int u = c * 64 + (kc & 63);
      float s  = (seg == 2) ? 0.025515518153991442f : 0.03608439182435161f;
      int off  = (seg == 0) ? 65536 : (seg == 1 ? 131072 : 262144);
      pk.h[e] = f2bf(wgt[off + u * 256 + w] * s);
    }
    ((int4*)Bw)[fid] = pk.v;
  } else if (fid < 40960) {
    int f2 = fid - 24576;
    int lane = f2 & 63;
    int ct = (f2 >> 6) & 15;
    int q = f2 >> 10;             // 0..15 = c*4 + kt
    int kt = q & 3, c = q >> 2;
    int w = ct * 16 + (lane & 15);
    int kh = (lane >> 4) * 8;
#pragma unroll
    for (int e = 0; e < 8; ++e) {
      int kc = kt * 32 + kh + e;       // 0..127
      int seg = kc >> 6;
      int u = c * 64 + (kc & 63);
      float s  = (seg == 0) ? 0.04419417382415922f : 0.025515518153991442f;
      int off  = (seg == 0) ? 0 : 196608;
      pk.h[e] = f2bf(wgt[off + u * 256 + w] * s);
    }
    ((int4*)Bw)[fid] = pk.v;
  }
}

// Per-buffer LDS map (int4 slots): T1 rt*384 + kt*64 + perm (rt 0..2, kt 0..5)
//                                  T0 1152 + kt*64 + perm   (kt 0..3)
// Buffer b at slot offset b*1408. Total 2816 int4 = 45056 B.
#define BUFSLOTS 1408
#define T0BASE 1152

struct X1Regs {
  float4 s;      // s1[u .. u+4)
  float4 v[3];   // v1[(u..u+4), 0..3) interleaved: f[3e+k]
};

static __device__ __forceinline__ void load_x1(
    X1Regs& r, const float* __restrict__ x1, int zrow, int ub, int rr)
{
  const float* base = x1 + (size_t)zrow * 1024;
  r.s = *(const float4*)(base + ub + rr * 4);
  const float4* pv = (const float4*)(base + 256 + 3 * ub + rr * 12);
#pragma unroll
  for (int i = 0; i < 3; ++i) r.v[i] = pv[i];
}

// thread (zl 0..15, rr 0..15) owns u-run [rr*4, rr*4+4) of the 64-u chunk.
// kc = sg*64 + rr*4 + e -> kt = sg*2 + (rr>>3), lh = (rr>>1)&3, half = rr&1.
static __device__ __forceinline__ void build_frags(
    const X1Regs& r, int zl, int rr, float s2, const float* v2, int4* ldsT)
{
  union { float4 q; float f[4]; } s1u;
  s1u.q = r.s;
  union { float4 q[3]; float f[12]; } v1u;
#pragma unroll
  for (int i = 0; i < 3; ++i) v1u.q[i] = r.v[i];
  const int lh   = (rr >> 1) & 3;
  const int kq   = rr >> 3;
  const int half = rr & 1;
  int2* lds2 = (int2*)ldsT;

  // ---- T1: seg 0..2 x comp k 0..2 ; row = 3*zl + k (0..47)
#pragma unroll
  for (int sg = 0; sg < 3; ++sg) {
#pragma unroll
    for (int k = 0; k < 3; ++k) {
      int row = 3 * zl + k;
      int kt  = sg * 2 + kq;
      int fl  = (((lh << 4) | (row & 15)) ^ (kt & 7)) ^ lh;
      int slot = (row >> 4) * 384 + kt * 64 + fl;
      float t[4];
      if (sg == 0) {                     // s1 * v2[k]      (-> W2)
#pragma unroll
        for (int e = 0; e < 4; ++e) t[e] = s1u.f[e] * v2[k];
      } else if (sg == 1) {              // v1[.,k] * s2    (-> W3)
#pragma unroll
        for (int e = 0; e < 4; ++e) t[e] = v1u.f[3 * e + k] * s2;
      } else {                           // (v1 x v2)[k]    (-> W5)
        int k1 = k + 1; if (k1 > 2) k1 -= 3;
        int k2 = k + 2; if (k2 > 2) k2 -= 3;
#pragma unroll
        for (int e = 0; e < 4; ++e)
          t[e] = v1u.f[3 * e + k1] * v2[k2] - v1u.f[3 * e + k2] * v2[k1];
      }
      union { unsigned short h[4]; int2 v; } pk;
#pragma unroll
      for (int e = 0; e < 4; ++e) pk.h[e] = f2bf(t[e]);
      lds2[slot * 2 + half] = pk.v;
    }
  }
  // ---- T0: seg 0..1 ; row = zl (0..15)
#pragma unroll
  for (int sg = 0; sg < 2; ++sg) {
    int kt = sg * 2 + kq;
    int fl = (((lh << 4) | zl) ^ (kt & 7)) ^ lh;
    int slot = T0BASE + kt * 64 + fl;
    float t[4];
    if (sg == 0) {                       // s1 * s2         (-> W1)
#pragma unroll
      for (int e = 0; e < 4; ++e) t[e] = s1u.f[e] * s2;
    } else {                             // v1 . v2         (-> W4)
#pragma unroll
      for (int e = 0; e < 4; ++e)
        t[e] = v1u.f[3 * e] * v2[0] + v1u.f[3 * e + 1] * v2[1]
             + v1u.f[3 * e + 2] * v2[2];
    }
    union { unsigned short h[4]; int2 v; } pk;
#pragma unroll
    for (int e = 0; e < 4; ++e) pk.h[e] = f2bf(t[e]);
    lds2[slot * 2 + half] = pk.v;
  }
}

// Burst-load this wave's ENTIRE per-chunk B slice: 20 int4 (80 VGPR).
// vb[0..11] = out1 kt 0..5 x {ct0, ct0+1}; vb[12..19] = out0 kt 0..3.
static __device__ __forceinline__ void load_Bburst(
    int4 (&vb)[20], const int4* __restrict__ B1v,
    const int4* __restrict__ B0v, int c, int ct0, int lane)
{
#pragma unroll
  for (int s = 0; s < 6; ++s) {
    const int4* p = B1v + ((size_t)((c * 6 + s) * 16 + ct0)) * 64 + lane;
    vb[s * 2]     = p[0];
    vb[s * 2 + 1] = p[64];
  }
#pragma unroll
  for (int s = 0; s < 4; ++s) {
    const int4* p = B0v + ((size_t)((c * 4 + s) * 16 + ct0)) * 64 + lane;
    vb[12 + s * 2]     = p[0];
    vb[12 + s * 2 + 1] = p[64];
  }
}

// Pure LDS+MFMA gemm for one u-chunk (no global loads).
static __device__ __forceinline__ void gemm_steps(
    const int4* __restrict__ buf, const int4 (&vb)[20], int lane,
    f32x4 acc1[3][2], f32x4 acc0[2])
{
#pragma unroll
  for (int kt = 0; kt < 6; ++kt) {
    int fl = (lane ^ (kt & 7)) ^ (lane >> 4);
    int4 a0 = buf[kt * 64 + fl];
    int4 a1 = buf[384 + kt * 64 + fl];
    int4 a2 = buf[768 + kt * 64 + fl];
    int4 a[3] = {a0, a1, a2};
#pragma unroll
    for (int rt = 0; rt < 3; ++rt) {
      bf16x8 av = asbf(a[rt]);
#pragma unroll
      for (int j = 0; j < 2; ++j)
        acc1[rt][j] = __builtin_amdgcn_mfma_f32_16x16x32_bf16(
            av, asbf(vb[kt * 2 + j]), acc1[rt][j], 0, 0, 0);
    }
  }
#pragma unroll
  for (int kt = 0; kt < 4; ++kt) {
    int fl = (lane ^ (kt & 7)) ^ (lane >> 4);
    int4 a0 = buf[T0BASE + kt * 64 + fl];
    bf16x8 av = asbf(a0);
#pragma unroll
    for (int j = 0; j < 2; ++j)
      acc0[j] = __builtin_amdgcn_mfma_f32_16x16x32_bf16(
          av, asbf(vb[12 + kt * 2 + j]), acc0[j], 0, 0, 0);
  }
}

// ---------------------------------------------------------------------------
// Main: 256 threads (4 waves, ct=2 each -> 128 cols), w-split across 2 blocks
// per z-tile (grid 2500). 16 z-rows, 4 u-chunks of 64, double-buffered LDS.
// Phase c: { burst B(c) + issue x1(c+2) | sched_barrier | build(c+1) |
//            gemm(c) | syncthreads }.
// ---------------------------------------------------------------------------
__global__ __launch_bounds__(256, 3) void tp_main(
    const float* __restrict__ x1, const float* __restrict__ x2,
    const int4* __restrict__ B1v, const int4* __restrict__ B0v,
    float* __restrict__ out)
{
  __shared__ int4 ldsT[2 * BUFSLOTS];   // 45056 bytes
  const int tid  = threadIdx.x;
  const int lane = tid & 63;
  const int wid  = tid >> 6;            // wave 0..3
  const int wh   = blockIdx.x & 1;      // w-half
  const int ct0  = wh * 8 + wid * 2;    // this wave's two 16-col tiles (global)
  const int z0   = (blockIdx.x >> 1) * 16;
  const int zl   = tid >> 4;            // T-build row (0..15)
  const int rr   = tid & 15;            // T-build u-run (0..15)

  f32x4 acc1[3][2];
  f32x4 acc0[2];
#pragma unroll
  for (int i = 0; i < 3; ++i)
#pragma unroll
    for (int j = 0; j < 2; ++j) acc1[i][j] = (f32x4){0.f, 0.f, 0.f, 0.f};
#pragma unroll
  for (int j = 0; j < 2; ++j) acc0[j] = (f32x4){0.f, 0.f, 0.f, 0.f};

  float4 x2v = ((const float4*)x2)[z0 + zl];
  const float s2 = x2v.x;
  float v2[3] = {x2v.y, x2v.z, x2v.w};

  X1Regs rA, rB;
  int4 vb[20];

  // prologue: x1(0), x1(1) in flight; build(0) -> buf0
  load_x1(rA, x1, z0 + zl, 0, rr);
  load_x1(rB, x1, z0 + zl, 64, rr);
  build_frags(rA, zl, rr, s2, v2, ldsT);
  __syncthreads();

  // ---- phase 0: B(0) burst; x1(2)->rA; build(1)<-rB -> buf1; gemm(0,buf0)
  load_Bburst(vb, B1v, B0v, 0, ct0, lane);
  load_x1(rA, x1, z0 + zl, 128, rr);
  __builtin_amdgcn_sched_barrier(0);
  build_frags(rB, zl, rr, s2, v2, ldsT + BUFSLOTS);
  gemm_steps(ldsT, vb, lane, acc1, acc0);
  __syncthreads();

  // ---- phase 1: B(1) burst; x1(3)->rB; build(2)<-rA -> buf0; gemm(1,buf1)
  load_Bburst(vb, B1v, B0v, 1, ct0, lane);
  load_x1(rB, x1, z0 + zl, 192, rr);
  __builtin_amdgcn_sched_barrier(0);
  build_frags(rA, zl, rr, s2, v2, ldsT);
  gemm_steps(ldsT + BUFSLOTS, vb, lane, acc1, acc0);
  __syncthreads();

  // ---- phase 2: B(2) burst; build(3)<-rB -> buf1; gemm(2,buf0)
  load_Bburst(vb, B1v, B0v, 2, ct0, lane);
  __builtin_amdgcn_sched_barrier(0);
  build_frags(rB, zl, rr, s2, v2, ldsT + BUFSLOTS);
  gemm_steps(ldsT, vb, lane, acc1, acc0);
  __syncthreads();

  // ---- phase 3: B(3) burst; gemm(3,buf1)
  load_Bburst(vb, B1v, B0v, 3, ct0, lane);
  __builtin_amdgcn_sched_barrier(0);
  gemm_steps(ldsT + BUFSLOTS, vb, lane, acc1, acc0);

  // ---- epilogue: accumulators are the final outputs
  const int col = lane & 15;
  const int rb  = (lane >> 4) * 4;       // C/D: col=lane&15, row=(lane>>4)*4+reg
#pragma unroll
  for (int j = 0; j < 2; ++j) {
    int w = (ct0 + j) * 16 + col;
#pragma unroll
    for (int rg = 0; rg < 4; ++rg) {
      int row = rb + rg;                 // zl 0..15
      out[(size_t)(z0 + row) * 1024 + w] = acc0[j][rg];
    }
  }
#pragma unroll
  for (int rt = 0; rt < 3; ++rt) {
#pragma unroll
    for (int j = 0; j < 2; ++j) {
      int w = (ct0 + j) * 16 + col;
#pragma unroll
      for (int rg = 0; rg < 4; ++rg) {
        int row = rt * 16 + rb + rg;     // 0..47 ; row = 3*zl + k
        int zz = row / 3;
        int k  = row - zz * 3;
        out[(size_t)(z0 + zz) * 1024 + 256 + w * 3 + k] = acc1[rt][j][rg];
      }
    }
  }
}

// ---------------------------------------------------------------------------
extern "C" void kernel_launch(void* const* d_in, const int* in_sizes, int n_in,
                              void* d_out, int out_size, void* d_ws, size_t ws_size,
                              hipStream_t stream) {
  const float* x1  = (const float*)d_in[0];   // (n, 1024) f32
  const float* x2  = (const float*)d_in[1];   // (n, 4)    f32
  const float* wgt = (const float*)d_in[2];   // (327680,) f32
  float* out = (float*)d_out;                 // (n, 1024) f32

  // ws: B1 fragments [0, 393216) + B0 fragments [393216, 655360)  (bf16)
  unsigned short* Bw = (unsigned short*)d_ws;
  const int4* B1v = (const int4*)Bw;
  const int4* B0v = B1v + 24576;

  int n = in_sizes[0] / 1024;                 // 20000 (divisible by 16)

  prep_weights<<<160, 256, 0, stream>>>(wgt, Bw);
  tp_main<<<(n / 16) * 2, 256, 0, stream>>>(x1, x2, B1v, B0v, out);
}